// Round 1
// baseline (368.527 us; speedup 1.0000x reference)
//
#include <hip/hip_runtime.h>
#include <hip/hip_bf16.h>
#include <stdint.h>

typedef unsigned short u16;
typedef __attribute__((ext_vector_type(8))) __bf16 bf16x8;
typedef __attribute__((ext_vector_type(4))) float f32x4;

#define S_LEN 2048
#define NHEAD 16
#define HDIM 64
#define DMODEL 1024
#define NBATCH 4
#define MTOK (NBATCH * S_LEN)   // 8192

// ---------- helpers ----------
__device__ __forceinline__ u16 f2bf(float f) {
    uint32_t u = __float_as_uint(f);
    u += 0x7fffu + ((u >> 16) & 1u);   // RNE
    return (u16)(u >> 16);
}

// async global->LDS, 16B per lane; lds dest must be wave-uniform base (+lane*16)
__device__ __forceinline__ void gld_lds16(const u16* g, u16* l) {
    __builtin_amdgcn_global_load_lds(
        (const __attribute__((address_space(1))) void*)g,
        (__attribute__((address_space(3))) void*)l, 16, 0, 0);
}

// ---------- fused fp32 -> bf16 cast: all 7 tensors in one launch ----------
__global__ __launch_bounds__(256) void cast_all(
        const float* __restrict__ q, const float* __restrict__ k, const float* __restrict__ v,
        const float* __restrict__ wq, const float* __restrict__ wk,
        const float* __restrict__ wv, const float* __restrict__ wo,
        u16* __restrict__ xq, u16* __restrict__ xk, u16* __restrict__ xv,
        u16* __restrict__ wqb, u16* __restrict__ wkb, u16* __restrict__ wvb,
        u16* __restrict__ wob) {
    size_t idx4 = (size_t)blockIdx.x * 256 + threadIdx.x;   // float4 index
    const float* src;
    u16* dst;
    size_t off;
    if (idx4 < (size_t)3 << 21) {
        int t = (int)(idx4 >> 21);
        off = (idx4 & ((1u << 21) - 1)) * 4;
        src = (t == 0) ? q : (t == 1) ? k : v;
        dst = (t == 0) ? xq : (t == 1) ? xk : xv;
    } else {
        size_t w = idx4 - ((size_t)3 << 21);
        int t = (int)(w >> 18);
        off = (w & ((1u << 18) - 1)) * 4;
        src = (t == 0) ? wq : (t == 1) ? wk : (t == 2) ? wv : wo;
        dst = (t == 0) ? wqb : (t == 1) ? wkb : (t == 2) ? wvb : wob;
    }
    float4 val = *(const float4*)(src + off);
    ushort4 o;
    o.x = f2bf(val.x); o.y = f2bf(val.y); o.z = f2bf(val.z); o.w = f2bf(val.w);
    *(ushort4*)(dst + off) = o;
}

// ---------- 256x256 8-phase GEMM (T2+T3+T4+T5 template) ----------
// out[m,n] = sum_k A[m,k]*W[n,k] + bias[n]
// 512 thr = 8 waves (2M x 4N); per-wave C = 128x64 = acc[8][4] f32x4.
// LDS: {A,B} x 2 dbuf x 2 groups x [128 rows x 64 cols], 64-col XOR swizzle
// (proven 0-conflict in previous rounds): slot c of row r holds global col8
// c^(r&7); staged by pre-swizzling the GLOBAL source col (lane&7)^(lane>>3).
// A group g = tile rows {g*64..+63, 128+g*64..+63} (the qm=g rows).
// B group g = tile rows {64j + g*32..+31, j=0..3}   (the qn=g rows).
// 8 phases / 2 K-tiles per iteration; phase = quadrant (qm,qn) of both
// K-tiles; each fragment ds_read ONCE per K-tile (12/4/8/0 read pattern),
// one half-tile (2 gld_lds/thread) staged per phase, raw s_barrier (no
// counter drain), vmcnt(4) only at phases 4/8 -> 2 half-tiles stay in
// flight across barriers. Stage->slot schedule hand-verified:
//   P1:A[b1][g1]<-t1  P2:B[b1][g1]<-t1  P3:A[b0][g0]<-t2  P4:B[b0][g0]<-t2
//   P5:B[b0][g1]<-t2  P6:A[b0][g1]<-t2  P7:A[b1][g0]<-t3  P8:B[b1][g0]<-t3
// (every slot staged after its last reader; every read covered by a
//  preceding vmcnt(4)+barrier). Last iter peeled with vmcnt(0) at P4.
#define KTILES (DMODEL / 64)   // 16

#define STAGE_A(buf, g, kt) do { \
    gld_lds16(gA0 + (size_t)(g) * 64 * DMODEL + (kt) * 64, &Asm[buf][g][cb0 * 64]); \
    gld_lds16(gA1 + (size_t)(g) * 64 * DMODEL + (kt) * 64, &Asm[buf][g][cb1 * 64]); \
} while (0)

#define STAGE_B(buf, g, kt) do { \
    gld_lds16(gB0 + (size_t)(g) * 32 * DMODEL + (kt) * 64, &Bsm[buf][g][cb0 * 64]); \
    gld_lds16(gB1 + (size_t)(g) * 32 * DMODEL + (kt) * 64, &Bsm[buf][g][cb1 * 64]); \
} while (0)

#define READ_A(buf, qm) do { \
    _Pragma("unroll") \
    for (int f = 0; f < 4; ++f) { \
        const u16* ap = &Asm[buf][qm][(wm * 64 + f * 16 + l16) * 64]; \
        af[f][0] = *(const bf16x8*)(ap + cA * 8); \
        af[f][1] = *(const bf16x8*)(ap + cB * 8); \
    } \
} while (0)

#define READ_B(buf, qn) do { \
    _Pragma("unroll") \
    for (int j = 0; j < 2; ++j) { \
        const u16* bp = &Bsm[buf][qn][(wn * 32 + j * 16 + l16) * 64]; \
        bfr[(qn) * 2 + j][0] = *(const bf16x8*)(bp + cA * 8); \
        bfr[(qn) * 2 + j][1] = *(const bf16x8*)(bp + cB * 8); \
    } \
} while (0)

#define PH_TAIL(qm, qn) do { \
    __builtin_amdgcn_s_barrier(); \
    __builtin_amdgcn_s_waitcnt(0xC07F);      /* lgkmcnt(0) */ \
    __builtin_amdgcn_sched_barrier(0); \
    __builtin_amdgcn_s_setprio(1); \
    _Pragma("unroll") \
    for (int f = 0; f < 4; ++f) \
        _Pragma("unroll") \
        for (int j = 0; j < 2; ++j) { \
            acc[(qm) * 4 + f][(qn) * 2 + j] = __builtin_amdgcn_mfma_f32_16x16x32_bf16( \
                af[f][0], bfr[(qn) * 2 + j][0], acc[(qm) * 4 + f][(qn) * 2 + j], 0, 0, 0); \
            acc[(qm) * 4 + f][(qn) * 2 + j] = __builtin_amdgcn_mfma_f32_16x16x32_bf16( \
                af[f][1], bfr[(qn) * 2 + j][1], acc[(qm) * 4 + f][(qn) * 2 + j], 0, 0, 0); \
        } \
    __builtin_amdgcn_s_setprio(0); \
    __builtin_amdgcn_s_barrier(); \
} while (0)

__device__ __forceinline__ void gemm_body256(const u16* __restrict__ A,
                                             const u16* __restrict__ W,
                                             const float* __restrict__ bias,
                                             void* __restrict__ outp, int mode,
                                             int m0, int n0) {
    __shared__ __align__(16) u16 Asm[2][2][128 * 64];
    __shared__ __align__(16) u16 Bsm[2][2][128 * 64];

    const int tid  = threadIdx.x;
    const int lane = tid & 63;
    const int wv   = tid >> 6;        // 0..7
    const int wm   = wv >> 2;         // 0..1
    const int wn   = wv & 3;          // 0..3
    const int l16  = lane & 15;
    const int quad = lane >> 4;

    // fragment-read swizzled col8
    const int cA = quad ^ (l16 & 7);          // k in [0,32)
    const int cB = (quad + 4) ^ (l16 & 7);    // k in [32,64)

    // staging: 8 lanes/row, pre-swizzled global col8
    const int sr = lane >> 3;
    const int sc = (lane & 7) ^ sr;
    const int cb0 = wv * 16;          // this wave's two 8-row chunks of a group
    const int cb1 = wv * 16 + 8;
    // group-local row lr -> global row: A: m0 + (lr>>6)*128 + g*64 + (lr&63)
    //                                   B: n0 + (lr>>5)*64  + g*32 + (lr&31)
    const u16* gA0 = A + (size_t)(m0 + (cb0 >> 6) * 128 + (cb0 & 63) + sr) * DMODEL + sc * 8;
    const u16* gA1 = A + (size_t)(m0 + (cb1 >> 6) * 128 + (cb1 & 63) + sr) * DMODEL + sc * 8;
    const u16* gB0 = W + (size_t)(n0 + (cb0 >> 5) * 64 + (cb0 & 31) + sr) * DMODEL + sc * 8;
    const u16* gB1 = W + (size_t)(n0 + (cb1 >> 5) * 64 + (cb1 & 31) + sr) * DMODEL + sc * 8;

    f32x4 acc[8][4];
#pragma unroll
    for (int i = 0; i < 8; ++i)
#pragma unroll
        for (int j = 0; j < 4; ++j) acc[i][j] = {};

    bf16x8 af[4][2];    // current qm's A fragments (reused across qm halves)
    bf16x8 bfr[4][2];   // full K-tile B fragments

    // prologue: T0 (all 4 halves) + T1's g0 halves; leave newest 2 in flight
    STAGE_A(0, 0, 0);
    STAGE_B(0, 0, 0);
    STAGE_B(0, 1, 0);
    STAGE_A(0, 1, 0);
    STAGE_A(1, 0, 1);
    STAGE_B(1, 0, 1);
    __builtin_amdgcn_s_waitcnt(0x0F74);   // vmcnt(4)
    __builtin_amdgcn_s_barrier();

#pragma unroll 1
    for (int i = 0; i < KTILES / 2 - 1; ++i) {
        const int t1 = 2 * i + 1, t2 = 2 * i + 2, t3 = 2 * i + 3;
        // ---- K-tile T0 (buf0) ----
        READ_A(0, 0); READ_B(0, 0); STAGE_A(1, 1, t1);            PH_TAIL(0, 0); // P1
        READ_B(0, 1);               STAGE_B(1, 1, t1);            PH_TAIL(0, 1); // P2
        READ_A(0, 1);               STAGE_A(0, 0, t2);            PH_TAIL(1, 0); // P3
        STAGE_B(0, 0, t2); __builtin_amdgcn_s_waitcnt(0x0F74);    PH_TAIL(1, 1); // P4
        // ---- K-tile T1 (buf1) ----
        READ_A(1, 0); READ_B(1, 0); STAGE_B(0, 1, t2);            PH_TAIL(0, 0); // P5
        READ_B(1, 1);               STAGE_A(0, 1, t2);            PH_TAIL(0, 1); // P6
        READ_A(1, 1);               STAGE_A(1, 0, t3);            PH_TAIL(1, 0); // P7
        STAGE_B(1, 0, t3); __builtin_amdgcn_s_waitcnt(0x0F74);    PH_TAIL(1, 1); // P8
    }
    // peeled last iteration: only T1's g1 halves remain to stage; full drain
    // at P4 (the counted wait would otherwise leave NEEDED halves in flight).
    READ_A(0, 0); READ_B(0, 0); STAGE_A(1, 1, KTILES - 1);        PH_TAIL(0, 0);
    READ_B(0, 1);               STAGE_B(1, 1, KTILES - 1);        PH_TAIL(0, 1);
    READ_A(0, 1);                                                 PH_TAIL(1, 0);
    __builtin_amdgcn_s_waitcnt(0x0F70);   /* vmcnt(0) */          PH_TAIL(1, 1);
    READ_A(1, 0); READ_B(1, 0);                                   PH_TAIL(0, 0);
    READ_B(1, 1);                                                 PH_TAIL(0, 1);
    READ_A(1, 1);                                                 PH_TAIL(1, 0);
                                                                  PH_TAIL(1, 1);

    // epilogue: m = m0 + wm*128 + (fm>>2)*64 + (fm&3)*16 + quad*4 + r
    //           n = n0 + wn*64  + (fn>>1)*32 + (fn&1)*16 + l16
#pragma unroll
    for (int fn = 0; fn < 4; ++fn) {
        const int n = n0 + wn * 64 + (fn >> 1) * 32 + (fn & 1) * 16 + l16;
        const float bvl = bias[n];
#pragma unroll
        for (int fm = 0; fm < 8; ++fm) {
            const int mb = m0 + wm * 128 + (fm >> 2) * 64 + (fm & 3) * 16 + quad * 4;
#pragma unroll
            for (int r = 0; r < 4; ++r) {
                const int m = mb + r;
                const float v = acc[fm][fn][r] + bvl;
                if (mode == 2) {
                    ((float*)outp)[(size_t)m * DMODEL + n] = v;
                } else {
                    const int b = m >> 11, s = m & (S_LEN - 1);
                    const int h = n >> 6, d = n & 63;
                    u16* o = (u16*)outp;
                    size_t idx = (mode == 0)
                        ? ((((size_t)(b * NHEAD + h)) * S_LEN + s) * HDIM + d)
                        : ((((size_t)(b * NHEAD + h)) * HDIM + d) * S_LEN + s);
                    o[idx] = f2bf(v);
                }
            }
        }
    }
}

#undef STAGE_A
#undef STAGE_B
#undef READ_A
#undef READ_B
#undef PH_TAIL

// XCD-locality: XCD (lid&7) owns 4 m-blocks x all 4 n-blocks -> its A panels
// (4 x 512 KB) + the whole 2 MiB weight fit the 4 MiB per-XCD L2.
__device__ __forceinline__ void gemm_coords256(int& m0, int& n0) {
    const int lid = blockIdx.x;        // 0..127
    const int xcd = lid & 7;
    const int s   = lid >> 3;          // 0..15
    n0 = (s & 3) * 256;
    m0 = (4 * xcd + (s >> 2)) * 256;
}

__global__ __launch_bounds__(512, 2) void gemm_qkv(
        const u16* __restrict__ xq, const u16* __restrict__ xk, const u16* __restrict__ xv,
        const u16* __restrict__ wq, const u16* __restrict__ wk, const u16* __restrict__ wv,
        const float* __restrict__ bq, const float* __restrict__ bk, const float* __restrict__ bv,
        u16* __restrict__ Qb, u16* __restrict__ Kb, u16* __restrict__ Vb) {
    int z = blockIdx.z;
    const u16* A   = (z == 0) ? xq : (z == 1) ? xk : xv;
    const u16* W   = (z == 0) ? wq : (z == 1) ? wk : wv;
    const float* b = (z == 0) ? bq : (z == 1) ? bk : bv;
    u16* out       = (z == 0) ? Qb : (z == 1) ? Kb : Vb;
    int m0, n0;
    gemm_coords256(m0, n0);
    gemm_body256(A, W, b, out, (z == 2) ? 1 : 0, m0, n0);
}

__global__ __launch_bounds__(512, 2) void gemm_one(
        const u16* __restrict__ A, const u16* __restrict__ W,
        const float* __restrict__ bias, void* __restrict__ out, int mode) {
    int m0, n0;
    gemm_coords256(m0, n0);
    gemm_body256(A, W, bias, out, mode, m0, n0);
}

// ---------- flash attention (v4, known-good: VGPR 64, zero spill) ----------
// 1 q-tile (16 queries) per wave; 64-key tiles; block-cooperative K/V LDS
// staging double-buffered via global_load_lds; XOR-swizzled layout; fixed-max
// log2-domain softmax; row sums via ones-operand MFMA; {g, 31-g} pairing ->
// exactly 33 iters/block. NOTE (R5/R6): 2-q-sets-per-wave variants need ~120
// live VGPRs and spill catastrophically under occupancy bounds — do not.
__global__ __launch_bounds__(256, 4) void flash_kernel(
        const u16* __restrict__ Q, const u16* __restrict__ K,
        const u16* __restrict__ Vt, u16* __restrict__ AO) {
    __shared__ __align__(16) u16 Ksm[2][64 * 64];
    __shared__ __align__(16) u16 Vsm[2][64 * 64];
    __shared__ __align__(16) u16 Psm[4][16 * 64];

    const int tid  = threadIdx.x;
    const int wv   = tid >> 6;
    const int lane = tid & 63;
    const int l16  = lane & 15;
    const int quad = lane >> 4;

    // XCD-pinning: all 16 blocks of a bh share (linear id % 8)
    const int lid   = blockIdx.x + 16 * blockIdx.y;   // 0..1023
    const int xcd   = lid & 7;
    const int slot  = lid >> 3;                        // 0..127
    const int bh    = xcd + 8 * (slot >> 4);           // 0..63
    const int g_idx = slot & 15;                       // 0..15

    const int h    = bh & (NHEAD - 1);
    const int b    = bh >> 4;
    const bool fwd = (h < 8);
    const int sgn  = fwd ? 1 : -1;
    const float slope2 = __builtin_amdgcn_exp2f(-(float)((h & 7) + 1) * 0.5731203125901445f)
                         * 1.4426950408889634f;
    const float cL = 0.18033688011112042f;   // log2(e)/8

    const u16* Kg = K + (size_t)bh * S_LEN * HDIM;
    const u16* Vg = Vt + (size_t)bh * HDIM * S_LEN;

    // staging lane constants: 8 lanes per row, col16 = (lane&7) ^ (lane>>3)
    const int sr = lane >> 3;
    const int sc = (lane & 7) ^ sr;
    const int r0 = 16 * wv;          // this wave stages rows r0..r0+15

    // fragment-read swizzled col16
    const int cA = quad ^ (l16 & 7);          // global col16 = quad
    const int cB = (quad + 4) ^ (l16 & 7);    // global col16 = quad+4

    // ALiBi per-(t,r) in-tile offset, fixed max 16 folded
    float brt[4][4];
#pragma unroll
    for (int t = 0; t < 4; t++)
#pragma unroll
        for (int r = 0; r < 4; r++)
            brt[t][r] = slope2 * (float)(sgn * (16 * t + l16 - (quad * 4 + r))) - 16.0f;

    // P scatter offsets (u16 units) — constant across all iterations
    int poff[4][4];
#pragma unroll
    for (int r = 0; r < 4; r++) {
        const int prow = quad * 4 + r;
        const int pr7  = prow & 7;
#pragma unroll
        for (int t = 0; t < 4; t++)
            poff[r][t] = prow * 64 + (((2 * t + (l16 >> 3)) ^ pr7) * 8) + (l16 & 7);
    }

    bf16x8 ones;
#pragma unroll
    for (int j = 0; j < 8; j++) ones[j] = (__bf16)1.0f;

    const float dkq = slope2 * (float)(sgn * 64);

#pragma unroll 1
    for (int half = 0; half < 2; half++) {
        const int g  = half ? (31 - g_idx) : g_idx;    // 64-query group 0..31
        const int q0 = g * 64 + wv * 16;
        const u16* Qp = Q + ((size_t)bh * S_LEN + q0) * HDIM;
        const bf16x8 aq0 = *(const bf16x8*)(Qp + l16 * HDIM + quad * 8);
        const bf16x8 aq1 = *(const bf16x8*)(Qp + l16 * HDIM + 32 + quad * 8);

        f32x4 o[4], osum = {};
#pragma unroll
        for (int dt = 0; dt < 4; dt++) o[dt] = {};

        const int kt0 = fwd ? 0 : g;
        const int kt1 = fwd ? g : (S_LEN / 64 - 1);

        __syncthreads();   // previous half's readers done before overwrite
        // incremental staging pointers
        const u16* kg = Kg + ((size_t)(kt0 * 64) + r0 + sr) * 64 + sc * 8;
        const u16* vg = Vg + (size_t)(r0 + sr) * S_LEN + kt0 * 64 + sc * 8;
        gld_lds16(kg,              &Ksm[0][r0 * 64]);
        gld_lds16(kg + 8 * 64,     &Ksm[0][(r0 + 8) * 64]);
        gld_lds16(vg,              &Vsm[0][r0 * 64]);
        gld_lds16(vg + 8 * S_LEN,  &Vsm[0][(r0 + 8) * 64]);
        kg += 64 * 64;
        vg += 64;

        float kq = slope2 * (float)(sgn * (kt0 * 64 - q0));

        int buf = 0;
        for (int kt = kt0; kt <= kt1; ++kt) {
            __builtin_amdgcn_s_waitcnt(0x0F70);   // vmcnt(0): buf staged
            __syncthreads();
            if (kt < kt1) {   // stage next tile into the other buffer
                gld_lds16(kg,             &Ksm[buf ^ 1][r0 * 64]);
                gld_lds16(kg + 8 * 64,    &Ksm[buf ^ 1][(r0 + 8) * 64]);
                gld_lds16(vg,             &Vsm[buf ^ 1][r0 * 64]);
                gld_lds16(vg + 8 * S_LEN, &Vsm[buf ^ 1][(r0 + 8) * 64]);
                kg += 64 * 64;
                vg += 64;
            }
            const u16* Ks = &Ksm[buf][0];
            const u16* Vs = &Vsm[buf][0];

            // QK^T from LDS
            f32x4 st[4];
#pragma unroll
            for (int t = 0; t < 4; t++) {
                const u16* kp = Ks + (16 * t + l16) * 64;
                bf16x8 k0 = *(const bf16x8*)(kp + cA * 8);
                bf16x8 k1 = *(const bf16x8*)(kp + cB * 8);
                f32x4 c = {};
                c = __builtin_amdgcn_mfma_f32_16x16x32_bf16(aq0, k0, c, 0, 0, 0);
                c = __builtin_amdgcn_mfma_f32_16x16x32_bf16(aq1, k1, c, 0, 0, 0);
                st[t] = c;
            }

            float p[4][4];
            if (kt == g) {   // diagonal tile: explicit mask
#pragma unroll
                for (int r = 0; r < 4; r++) {
                    const int qg = q0 + quad * 4 + r;
#pragma unroll
                    for (int t = 0; t < 4; t++) {
                        const int kg2 = kt * 64 + 16 * t + l16;
                        const bool ok = fwd ? (kg2 <= qg) : (kg2 >= qg);
                        float s2 = fmaf(st[t][r], cL, brt[t][r] + kq);
                        p[t][r] = ok ? __builtin_amdgcn_exp2f(s2) : 0.0f;
                    }
                }
            } else {
#pragma unroll
                for (int r = 0; r < 4; r++)
#pragma unroll
                    for (int t = 0; t < 4; t++)
                        p[t][r] = __builtin_amdgcn_exp2f(fmaf(st[t][r], cL, brt[t][r] + kq));
            }
            kq += dkq;

            // P (C-layout) -> swizzled LDS -> A-operand layout (wave-private)
            u16* Pw = &Psm[wv][0];
#pragma unroll
            for (int r = 0; r < 4; r++)
#pragma unroll
                for (int t = 0; t < 4; t++)
                    Pw[poff[r][t]] = f2bf(p[t][r]);
            __builtin_amdgcn_s_waitcnt(0xC07F);   // lgkmcnt(0); wave-private
            bf16x8 pf0 = *(const bf16x8*)(&Pw[l16 * 64 + cA * 8]);
            bf16x8 pf1 = *(const bf16x8*)(&Pw[l16 * 64 + cB * 8]);

            // PV from LDS V
#pragma unroll
            for (int dt = 0; dt < 4; dt++) {
                const u16* vp = Vs + (dt * 16 + l16) * 64;
                bf16x8 v0 = *(const bf16x8*)(vp + cA * 8);
                bf16x8 v1 = *(const bf16x8*)(vp + cB * 8);
                o[dt] = __builtin_amdgcn_mfma_f32_16x16x32_bf16(pf0, v0, o[dt], 0, 0, 0);
                o[dt] = __builtin_amdgcn_mfma_f32_16x16x32_bf16(pf1, v1, o[dt], 0, 0, 0);
            }
            osum = __builtin_amdgcn_mfma_f32_16x16x32_bf16(pf0, ones, osum, 0, 0, 0);
            osum = __builtin_amdgcn_mfma_f32_16x16x32_bf16(pf1, ones, osum, 0, 0, 0);
            buf ^= 1;
        }

        // epilogue: AO[b, s, h*64+d] bf16
#pragma unroll
        for (int r = 0; r < 4; r++) {
            float inv = 1.0f / osum[r];
            int qg = q0 + quad * 4 + r;
            u16* op = AO + ((size_t)b * S_LEN + qg) * DMODEL + h * HDIM;
#pragma unroll
            for (int dt = 0; dt < 4; dt++)
                op[dt * 16 + l16] = f2bf(o[dt][r] * inv);
        }
    }
}

extern "C" void kernel_launch(void* const* d_in, const int* in_sizes, int n_in,
                              void* d_out, int out_size, void* d_ws, size_t ws_size,
                              hipStream_t stream) {
    const float* query = (const float*)d_in[0];
    const float* key   = (const float*)d_in[1];
    const float* value = (const float*)d_in[2];
    const float* Wq    = (const float*)d_in[3];
    const float* bq    = (const float*)d_in[4];
    const float* Wk    = (const float*)d_in[5];
    const float* bk    = (const float*)d_in[6];
    const float* Wv    = (const float*)d_in[7];
    const float* bv    = (const float*)d_in[8];
    const float* Wo    = (const float*)d_in[9];
    const float* bo    = (const float*)d_in[10];

    const size_t Xe = (size_t)MTOK * DMODEL;    // 2^23 elems
    const size_t We = (size_t)DMODEL * DMODEL;  // 2^20 elems
    u16* xq  = (u16*)d_ws;
    u16* xk  = xq + Xe;
    u16* xv  = xk + Xe;
    u16* wqb = xv + Xe;
    u16* wkb = wqb + We;
    u16* wvb = wkb + We;
    u16* wob = wvb + We;
    u16* Qb  = wob + We;
    u16* Kb  = Qb + Xe;
    u16* Vb  = Kb + Xe;   // transposed [B,H,D,S]
    u16* AO  = Vb + Xe;

    cast_all<<<dim3(28672), dim3(256), 0, stream>>>(
        query, key, value, Wq, Wk, Wv, Wo,
        xq, xk, xv, wqb, wkb, wvb, wob);

    gemm_qkv<<<dim3(128, 1, 3), dim3(512), 0, stream>>>(
        xq, xk, xv, wqb, wkb, wvb, bq, bk, bv, Qb, Kb, Vb);

    flash_kernel<<<dim3(16, NBATCH * NHEAD), dim3(256), 0, stream>>>(Qb, Kb, Vb, AO);

    gemm_one<<<dim3(128), dim3(512), 0, stream>>>(AO, wob, bo, d_out, 2);
}

// Round 2
// 321.416 us; speedup vs baseline: 1.1466x; 1.1466x over previous
//
#include <hip/hip_runtime.h>
#include <hip/hip_bf16.h>
#include <stdint.h>

typedef unsigned short u16;
typedef __attribute__((ext_vector_type(8))) __bf16 bf16x8;
typedef __attribute__((ext_vector_type(4))) float f32x4;

#define S_LEN 2048
#define NHEAD 16
#define HDIM 64
#define DMODEL 1024
#define NBATCH 4
#define MTOK (NBATCH * S_LEN)   // 8192

// ---------- helpers ----------
__device__ __forceinline__ u16 f2bf(float f) {
    uint32_t u = __float_as_uint(f);
    u += 0x7fffu + ((u >> 16) & 1u);   // RNE
    return (u16)(u >> 16);
}

// async global->LDS, 16B per lane; lds dest must be wave-uniform base (+lane*16)
__device__ __forceinline__ void gld_lds16(const u16* g, u16* l) {
    __builtin_amdgcn_global_load_lds(
        (const __attribute__((address_space(1))) void*)g,
        (__attribute__((address_space(3))) void*)l, 16, 0, 0);
}

// ---------- fused fp32 -> bf16 cast: all 7 tensors in one launch ----------
__global__ __launch_bounds__(256) void cast_all(
        const float* __restrict__ q, const float* __restrict__ k, const float* __restrict__ v,
        const float* __restrict__ wq, const float* __restrict__ wk,
        const float* __restrict__ wv, const float* __restrict__ wo,
        u16* __restrict__ xq, u16* __restrict__ xk, u16* __restrict__ xv,
        u16* __restrict__ wqb, u16* __restrict__ wkb, u16* __restrict__ wvb,
        u16* __restrict__ wob) {
    size_t idx4 = (size_t)blockIdx.x * 256 + threadIdx.x;   // float4 index
    const float* src;
    u16* dst;
    size_t off;
    if (idx4 < (size_t)3 << 21) {
        int t = (int)(idx4 >> 21);
        off = (idx4 & ((1u << 21) - 1)) * 4;
        src = (t == 0) ? q : (t == 1) ? k : v;
        dst = (t == 0) ? xq : (t == 1) ? xk : xv;
    } else {
        size_t w = idx4 - ((size_t)3 << 21);
        int t = (int)(w >> 18);
        off = (w & ((1u << 18) - 1)) * 4;
        src = (t == 0) ? wq : (t == 1) ? wk : (t == 2) ? wv : wo;
        dst = (t == 0) ? wqb : (t == 1) ? wkb : (t == 2) ? wvb : wob;
    }
    float4 val = *(const float4*)(src + off);
    ushort4 o;
    o.x = f2bf(val.x); o.y = f2bf(val.y); o.z = f2bf(val.z); o.w = f2bf(val.w);
    *(ushort4*)(dst + off) = o;
}

// ---------- GEMM: out[m,n] = sum_k A[m,k]*W[n,k] + bias[n] ----------
// Proven 128x128/BK=64 structure (R0: 24% MfmaUtil, 0 bank conflicts,
// FETCH = exact working set) + T3-minimum double-buffer:
//   prologue: STAGE(buf0, k=0); vmcnt(0); barrier;
//   loop:     STAGE(buf^1, k+1); ds_read buf; 32 MFMA; vmcnt(0); barrier
// Stage issued BEFORE compute so global->LDS latency hides under the MFMAs;
// vmcnt(0) only at the END of the iteration; ONE barrier per K-step (reads
// of buf complete before each wave's MFMA lgkm-waits, so the end barrier
// alone protects the overwrite). LDS 32->64 KiB, still 2 blocks/CU.
// LDS layout = proven 64-col XOR swizzle: logical col8 c of row r stored at
// slot c ^ (r&7); staged by fetching global col (lane&7)^(lane>>3); fragment
// b128 reads at quad^(l16&7) / (quad+4)^(l16&7) — 0 conflicts (R7 prev sess).
#define TM 128
#define TN 128
#define BK 64

__device__ __forceinline__ void gemm_body(const u16* __restrict__ A,
                                          const u16* __restrict__ W,
                                          const float* __restrict__ bias,
                                          void* __restrict__ outp, int mode,
                                          int m0, int n0) {
    __shared__ __align__(16) u16 As[2][TM * BK];
    __shared__ __align__(16) u16 Bs[2][TM * BK];
    const int tid  = threadIdx.x;
    const int lane = tid & 63;
    const int wv   = tid >> 6;
    const int l16  = lane & 15;
    const int quad = lane >> 4;
    const int wm   = (wv >> 1) * 64;
    const int wn   = (wv & 1) * 64;

    f32x4 acc[4][4];
#pragma unroll
    for (int i = 0; i < 4; i++)
#pragma unroll
        for (int j = 0; j < 4; j++) acc[i][j] = {};

    // staging: one gld covers 8 rows x 64 cols (64 lanes x 16B). 8 lanes/row.
    const int sr  = lane >> 3;                 // row within 8-row group
    const int sc7 = (lane & 7) ^ sr;           // swizzled source col8
    // wave wv stages rows [wv*32, wv*32+32) of A and B (4 glds each)
    const u16* gA = A + (size_t)(m0 + wv * 32 + sr) * DMODEL + sc7 * 8;
    const u16* gB = W + (size_t)(n0 + wv * 32 + sr) * DMODEL + sc7 * 8;
    const int lofs = wv * 32 * BK;             // wave-uniform LDS offset

    // fragment-read swizzled col8
    const int cA = quad ^ (l16 & 7);          // k in [0,32)
    const int cB = (quad + 4) ^ (l16 & 7);    // k in [32,64)

    // prologue: stage K-tile 0 into buf 0, drain, barrier
#pragma unroll
    for (int g = 0; g < 4; g++) {
        gld_lds16(gA + (size_t)(g * 8) * DMODEL, &As[0][lofs + g * 8 * BK]);
        gld_lds16(gB + (size_t)(g * 8) * DMODEL, &Bs[0][lofs + g * 8 * BK]);
    }
    __builtin_amdgcn_s_waitcnt(0x0F70);   // vmcnt(0)
    __syncthreads();

    int buf = 0;
    for (int kb = 0; kb < DMODEL; kb += BK) {
        const bool more = (kb + BK < DMODEL);
        if (more) {   // stage NEXT tile into the other buffer, issue-early
#pragma unroll
            for (int g = 0; g < 4; g++) {
                gld_lds16(gA + kb + BK + (size_t)(g * 8) * DMODEL,
                          &As[buf ^ 1][lofs + g * 8 * BK]);
                gld_lds16(gB + kb + BK + (size_t)(g * 8) * DMODEL,
                          &Bs[buf ^ 1][lofs + g * 8 * BK]);
            }
        }
        __builtin_amdgcn_sched_barrier(0);   // pin stage-issue before compute

        bf16x8 af0[4], af1[4], bf0[4], bf1[4];
#pragma unroll
        for (int i = 0; i < 4; i++) {
            const u16* ap = &As[buf][(wm + i * 16 + l16) * BK];
            af0[i] = *(const bf16x8*)(ap + cA * 8);
            af1[i] = *(const bf16x8*)(ap + cB * 8);
        }
#pragma unroll
        for (int j = 0; j < 4; j++) {
            const u16* bp = &Bs[buf][(wn + j * 16 + l16) * BK];
            bf0[j] = *(const bf16x8*)(bp + cA * 8);
            bf1[j] = *(const bf16x8*)(bp + cB * 8);
        }
#pragma unroll
        for (int i = 0; i < 4; i++)
#pragma unroll
            for (int j = 0; j < 4; j++)
                acc[i][j] = __builtin_amdgcn_mfma_f32_16x16x32_bf16(af0[i], bf0[j], acc[i][j], 0, 0, 0);
#pragma unroll
        for (int i = 0; i < 4; i++)
#pragma unroll
            for (int j = 0; j < 4; j++)
                acc[i][j] = __builtin_amdgcn_mfma_f32_16x16x32_bf16(af1[i], bf1[j], acc[i][j], 0, 0, 0);

        if (more) __builtin_amdgcn_s_waitcnt(0x0F70);   // vmcnt(0): next staged
        __syncthreads();
        buf ^= 1;
    }

#pragma unroll
    for (int j = 0; j < 4; j++) {
        int n = n0 + wn + j * 16 + l16;
        float bv = bias[n];
#pragma unroll
        for (int i = 0; i < 4; i++) {
            int mbase = m0 + wm + i * 16 + quad * 4;
#pragma unroll
            for (int r = 0; r < 4; r++) {
                int m = mbase + r;
                float v = acc[i][j][r] + bv;
                if (mode == 2) {
                    ((float*)outp)[(size_t)m * DMODEL + n] = v;
                } else {
                    int b = m >> 11, s = m & (S_LEN - 1);
                    int h = n >> 6, d = n & 63;
                    u16* o = (u16*)outp;
                    size_t idx = (mode == 0)
                        ? ((((size_t)(b * NHEAD + h)) * S_LEN + s) * HDIM + d)
                        : ((((size_t)(b * NHEAD + h)) * HDIM + d) * S_LEN + s);
                    o[idx] = f2bf(v);
                }
            }
        }
    }
}

// XCD-locality swizzle: XCD (lid&7) owns m-blocks [8*xcd, 8*xcd+8) for ALL n.
__device__ __forceinline__ void gemm_coords(int& m0, int& n0) {
    const int lid = blockIdx.x + 8 * blockIdx.y;   // 0..511
    const int xcd = lid & 7;
    const int s   = lid >> 3;                      // 0..63
    n0 = (s & 7) * TN;
    m0 = ((s >> 3) + 8 * xcd) * TM;
}

__global__ __launch_bounds__(256) void gemm_qkv(
        const u16* __restrict__ xq, const u16* __restrict__ xk, const u16* __restrict__ xv,
        const u16* __restrict__ wq, const u16* __restrict__ wk, const u16* __restrict__ wv,
        const float* __restrict__ bq, const float* __restrict__ bk, const float* __restrict__ bv,
        u16* __restrict__ Qb, u16* __restrict__ Kb, u16* __restrict__ Vb) {
    int z = blockIdx.z;
    const u16* A   = (z == 0) ? xq : (z == 1) ? xk : xv;
    const u16* W   = (z == 0) ? wq : (z == 1) ? wk : wv;
    const float* b = (z == 0) ? bq : (z == 1) ? bk : bv;
    u16* out       = (z == 0) ? Qb : (z == 1) ? Kb : Vb;
    int m0, n0;
    gemm_coords(m0, n0);
    gemm_body(A, W, b, out, (z == 2) ? 1 : 0, m0, n0);
}

__global__ __launch_bounds__(256) void gemm_one(
        const u16* __restrict__ A, const u16* __restrict__ W,
        const float* __restrict__ bias, void* __restrict__ out, int mode) {
    int m0, n0;
    gemm_coords(m0, n0);
    gemm_body(A, W, bias, out, mode, m0, n0);
}

// ---------- flash attention (v4, known-good: VGPR 64, zero spill) ----------
// 1 q-tile (16 queries) per wave; 64-key tiles; block-cooperative K/V LDS
// staging double-buffered via global_load_lds; XOR-swizzled layout; fixed-max
// log2-domain softmax; row sums via ones-operand MFMA; {g, 31-g} pairing ->
// exactly 33 iters/block. NOTE (R5/R6): 2-q-sets-per-wave variants need ~120
// live VGPRs and spill catastrophically under occupancy bounds — do not.
__global__ __launch_bounds__(256, 4) void flash_kernel(
        const u16* __restrict__ Q, const u16* __restrict__ K,
        const u16* __restrict__ Vt, u16* __restrict__ AO) {
    __shared__ __align__(16) u16 Ksm[2][64 * 64];
    __shared__ __align__(16) u16 Vsm[2][64 * 64];
    __shared__ __align__(16) u16 Psm[4][16 * 64];

    const int tid  = threadIdx.x;
    const int wv   = tid >> 6;
    const int lane = tid & 63;
    const int l16  = lane & 15;
    const int quad = lane >> 4;

    // XCD-pinning: all 16 blocks of a bh share (linear id % 8)
    const int lid   = blockIdx.x + 16 * blockIdx.y;   // 0..1023
    const int xcd   = lid & 7;
    const int slot  = lid >> 3;                        // 0..127
    const int bh    = xcd + 8 * (slot >> 4);           // 0..63
    const int g_idx = slot & 15;                       // 0..15

    const int h    = bh & (NHEAD - 1);
    const int b    = bh >> 4;
    const bool fwd = (h < 8);
    const int sgn  = fwd ? 1 : -1;
    const float slope2 = __builtin_amdgcn_exp2f(-(float)((h & 7) + 1) * 0.5731203125901445f)
                         * 1.4426950408889634f;
    const float cL = 0.18033688011112042f;   // log2(e)/8

    const u16* Kg = K + (size_t)bh * S_LEN * HDIM;
    const u16* Vg = Vt + (size_t)bh * HDIM * S_LEN;

    // staging lane constants: 8 lanes per row, col16 = (lane&7) ^ (lane>>3)
    const int sr = lane >> 3;
    const int sc = (lane & 7) ^ sr;
    const int r0 = 16 * wv;          // this wave stages rows r0..r0+15

    // fragment-read swizzled col16
    const int cA = quad ^ (l16 & 7);          // global col16 = quad
    const int cB = (quad + 4) ^ (l16 & 7);    // global col16 = quad+4

    // ALiBi per-(t,r) in-tile offset, fixed max 16 folded
    float brt[4][4];
#pragma unroll
    for (int t = 0; t < 4; t++)
#pragma unroll
        for (int r = 0; r < 4; r++)
            brt[t][r] = slope2 * (float)(sgn * (16 * t + l16 - (quad * 4 + r))) - 16.0f;

    // P scatter offsets (u16 units) — constant across all iterations
    int poff[4][4];
#pragma unroll
    for (int r = 0; r < 4; r++) {
        const int prow = quad * 4 + r;
        const int pr7  = prow & 7;
#pragma unroll
        for (int t = 0; t < 4; t++)
            poff[r][t] = prow * 64 + (((2 * t + (l16 >> 3)) ^ pr7) * 8) + (l16 & 7);
    }

    bf16x8 ones;
#pragma unroll
    for (int j = 0; j < 8; j++) ones[j] = (__bf16)1.0f;

    const float dkq = slope2 * (float)(sgn * 64);

#pragma unroll 1
    for (int half = 0; half < 2; half++) {
        const int g  = half ? (31 - g_idx) : g_idx;    // 64-query group 0..31
        const int q0 = g * 64 + wv * 16;
        const u16* Qp = Q + ((size_t)bh * S_LEN + q0) * HDIM;
        const bf16x8 aq0 = *(const bf16x8*)(Qp + l16 * HDIM + quad * 8);
        const bf16x8 aq1 = *(const bf16x8*)(Qp + l16 * HDIM + 32 + quad * 8);

        f32x4 o[4], osum = {};
#pragma unroll
        for (int dt = 0; dt < 4; dt++) o[dt] = {};

        const int kt0 = fwd ? 0 : g;
        const int kt1 = fwd ? g : (S_LEN / 64 - 1);

        __syncthreads();   // previous half's readers done before overwrite
        // incremental staging pointers
        const u16* kg = Kg + ((size_t)(kt0 * 64) + r0 + sr) * 64 + sc * 8;
        const u16* vg = Vg + (size_t)(r0 + sr) * S_LEN + kt0 * 64 + sc * 8;
        gld_lds16(kg,              &Ksm[0][r0 * 64]);
        gld_lds16(kg + 8 * 64,     &Ksm[0][(r0 + 8) * 64]);
        gld_lds16(vg,              &Vsm[0][r0 * 64]);
        gld_lds16(vg + 8 * S_LEN,  &Vsm[0][(r0 + 8) * 64]);
        kg += 64 * 64;
        vg += 64;

        float kq = slope2 * (float)(sgn * (kt0 * 64 - q0));

        int buf = 0;
        for (int kt = kt0; kt <= kt1; ++kt) {
            __builtin_amdgcn_s_waitcnt(0x0F70);   // vmcnt(0): buf staged
            __syncthreads();
            if (kt < kt1) {   // stage next tile into the other buffer
                gld_lds16(kg,             &Ksm[buf ^ 1][r0 * 64]);
                gld_lds16(kg + 8 * 64,    &Ksm[buf ^ 1][(r0 + 8) * 64]);
                gld_lds16(vg,             &Vsm[buf ^ 1][r0 * 64]);
                gld_lds16(vg + 8 * S_LEN, &Vsm[buf ^ 1][(r0 + 8) * 64]);
                kg += 64 * 64;
                vg += 64;
            }
            const u16* Ks = &Ksm[buf][0];
            const u16* Vs = &Vsm[buf][0];

            // QK^T from LDS
            f32x4 st[4];
#pragma unroll
            for (int t = 0; t < 4; t++) {
                const u16* kp = Ks + (16 * t + l16) * 64;
                bf16x8 k0 = *(const bf16x8*)(kp + cA * 8);
                bf16x8 k1 = *(const bf16x8*)(kp + cB * 8);
                f32x4 c = {};
                c = __builtin_amdgcn_mfma_f32_16x16x32_bf16(aq0, k0, c, 0, 0, 0);
                c = __builtin_amdgcn_mfma_f32_16x16x32_bf16(aq1, k1, c, 0, 0, 0);
                st[t] = c;
            }

            float p[4][4];
            if (kt == g) {   // diagonal tile: explicit mask
#pragma unroll
                for (int r = 0; r < 4; r++) {
                    const int qg = q0 + quad * 4 + r;
#pragma unroll
                    for (int t = 0; t < 4; t++) {
                        const int kg2 = kt * 64 + 16 * t + l16;
                        const bool ok = fwd ? (kg2 <= qg) : (kg2 >= qg);
                        float s2 = fmaf(st[t][r], cL, brt[t][r] + kq);
                        p[t][r] = ok ? __builtin_amdgcn_exp2f(s2) : 0.0f;
                    }
                }
            } else {
#pragma unroll
                for (int r = 0; r < 4; r++)
#pragma unroll
                    for (int t = 0; t < 4; t++)
                        p[t][r] = __builtin_amdgcn_exp2f(fmaf(st[t][r], cL, brt[t][r] + kq));
            }
            kq += dkq;

            // P (C-layout) -> swizzled LDS -> A-operand layout (wave-private)
            u16* Pw = &Psm[wv][0];
#pragma unroll
            for (int r = 0; r < 4; r++)
#pragma unroll
                for (int t = 0; t < 4; t++)
                    Pw[poff[r][t]] = f2bf(p[t][r]);
            __builtin_amdgcn_s_waitcnt(0xC07F);   // lgkmcnt(0); wave-private
            bf16x8 pf0 = *(const bf16x8*)(&Pw[l16 * 64 + cA * 8]);
            bf16x8 pf1 = *(const bf16x8*)(&Pw[l16 * 64 + cB * 8]);

            // PV from LDS V
#pragma unroll
            for (int dt = 0; dt < 4; dt++) {
                const u16* vp = Vs + (dt * 16 + l16) * 64;
                bf16x8 v0 = *(const bf16x8*)(vp + cA * 8);
                bf16x8 v1 = *(const bf16x8*)(vp + cB * 8);
                o[dt] = __builtin_amdgcn_mfma_f32_16x16x32_bf16(pf0, v0, o[dt], 0, 0, 0);
                o[dt] = __builtin_amdgcn_mfma_f32_16x16x32_bf16(pf1, v1, o[dt], 0, 0, 0);
            }
            osum = __builtin_amdgcn_mfma_f32_16x16x32_bf16(pf0, ones, osum, 0, 0, 0);
            osum = __builtin_amdgcn_mfma_f32_16x16x32_bf16(pf1, ones, osum, 0, 0, 0);
            buf ^= 1;
        }

        // epilogue: AO[b, s, h*64+d] bf16
#pragma unroll
        for (int r = 0; r < 4; r++) {
            float inv = 1.0f / osum[r];
            int qg = q0 + quad * 4 + r;
            u16* op = AO + ((size_t)b * S_LEN + qg) * DMODEL + h * HDIM;
#pragma unroll
            for (int dt = 0; dt < 4; dt++)
                op[dt * 16 + l16] = f2bf(o[dt][r] * inv);
        }
    }
}

extern "C" void kernel_launch(void* const* d_in, const int* in_sizes, int n_in,
                              void* d_out, int out_size, void* d_ws, size_t ws_size,
                              hipStream_t stream) {
    const float* query = (const float*)d_in[0];
    const float* key   = (const float*)d_in[1];
    const float* value = (const float*)d_in[2];
    const float* Wq    = (const float*)d_in[3];
    const float* bq    = (const float*)d_in[4];
    const float* Wk    = (const float*)d_in[5];
    const float* bk    = (const float*)d_in[6];
    const float* Wv    = (const float*)d_in[7];
    const float* bv    = (const float*)d_in[8];
    const float* Wo    = (const float*)d_in[9];
    const float* bo    = (const float*)d_in[10];

    const size_t Xe = (size_t)MTOK * DMODEL;    // 2^23 elems
    const size_t We = (size_t)DMODEL * DMODEL;  // 2^20 elems
    u16* xq  = (u16*)d_ws;
    u16* xk  = xq + Xe;
    u16* xv  = xk + Xe;
    u16* wqb = xv + Xe;
    u16* wkb = wqb + We;
    u16* wvb = wkb + We;
    u16* wob = wvb + We;
    u16* Qb  = wob + We;
    u16* Kb  = Qb + Xe;
    u16* Vb  = Kb + Xe;   // transposed [B,H,D,S]
    u16* AO  = Vb + Xe;

    cast_all<<<dim3(28672), dim3(256), 0, stream>>>(
        query, key, value, Wq, Wk, Wv, Wo,
        xq, xk, xv, wqb, wkb, wvb, wob);

    gemm_qkv<<<dim3(DMODEL / TN, MTOK / TM, 3), dim3(256), 0, stream>>>(
        xq, xk, xv, wqb, wkb, wvb, bq, bk, bv, Qb, Kb, Vb);

    flash_kernel<<<dim3(16, NBATCH * NHEAD), dim3(256), 0, stream>>>(Qb, Kb, Vb, AO);

    gemm_one<<<dim3(DMODEL / TN, MTOK / TM, 1), dim3(256), 0, stream>>>(AO, wob, bo, d_out, 2);
}

// Round 3
// 309.741 us; speedup vs baseline: 1.1898x; 1.0377x over previous
//
#include <hip/hip_runtime.h>
#include <hip/hip_bf16.h>
#include <stdint.h>

typedef unsigned short u16;
typedef __attribute__((ext_vector_type(8))) __bf16 bf16x8;
typedef __attribute__((ext_vector_type(4))) __bf16 bf16x4;
typedef __attribute__((ext_vector_type(4))) float f32x4;

#define S_LEN 2048
#define NHEAD 16
#define HDIM 64
#define DMODEL 1024
#define NBATCH 4
#define MTOK (NBATCH * S_LEN)   // 8192

// ---------- helpers ----------
__device__ __forceinline__ u16 f2bf(float f) {
    uint32_t u = __float_as_uint(f);
    u += 0x7fffu + ((u >> 16) & 1u);   // RNE
    return (u16)(u >> 16);
}

// async global->LDS, 16B per lane; lds dest must be wave-uniform base (+lane*16)
__device__ __forceinline__ void gld_lds16(const u16* g, u16* l) {
    __builtin_amdgcn_global_load_lds(
        (const __attribute__((address_space(1))) void*)g,
        (__attribute__((address_space(3))) void*)l, 16, 0, 0);
}

// ---------- fused fp32 -> bf16 cast: all 7 tensors in one launch ----------
__global__ __launch_bounds__(256) void cast_all(
        const float* __restrict__ q, const float* __restrict__ k, const float* __restrict__ v,
        const float* __restrict__ wq, const float* __restrict__ wk,
        const float* __restrict__ wv, const float* __restrict__ wo,
        u16* __restrict__ xq, u16* __restrict__ xk, u16* __restrict__ xv,
        u16* __restrict__ wqb, u16* __restrict__ wkb, u16* __restrict__ wvb,
        u16* __restrict__ wob) {
    size_t idx4 = (size_t)blockIdx.x * 256 + threadIdx.x;   // float4 index
    const float* src;
    u16* dst;
    size_t off;
    if (idx4 < (size_t)3 << 21) {
        int t = (int)(idx4 >> 21);
        off = (idx4 & ((1u << 21) - 1)) * 4;
        src = (t == 0) ? q : (t == 1) ? k : v;
        dst = (t == 0) ? xq : (t == 1) ? xk : xv;
    } else {
        size_t w = idx4 - ((size_t)3 << 21);
        int t = (int)(w >> 18);
        off = (w & ((1u << 18) - 1)) * 4;
        src = (t == 0) ? wq : (t == 1) ? wk : (t == 2) ? wv : wo;
        dst = (t == 0) ? wqb : (t == 1) ? wkb : (t == 2) ? wvb : wob;
    }
    float4 val = *(const float4*)(src + off);
    ushort4 o;
    o.x = f2bf(val.x); o.y = f2bf(val.y); o.z = f2bf(val.z); o.w = f2bf(val.w);
    *(ushort4*)(dst + off) = o;
}

// ---------- GEMM: out[m,n] = sum_k A[m,k]*W[n,k] + bias[n] ----------
// Proven 128x128/BK=64 + T3-minimum double-buffer (R2: verified win):
//   prologue: STAGE(buf0, k=0); vmcnt(0); barrier;
//   loop:     STAGE(buf^1, k+1); ds_read buf; 32 MFMA; vmcnt(0); barrier
// LDS layout = proven 64-col XOR swizzle (0 conflicts).
#define TM 128
#define TN 128
#define BK 64

__device__ __forceinline__ void gemm_body(const u16* __restrict__ A,
                                          const u16* __restrict__ W,
                                          const float* __restrict__ bias,
                                          void* __restrict__ outp, int mode,
                                          int m0, int n0) {
    __shared__ __align__(16) u16 As[2][TM * BK];
    __shared__ __align__(16) u16 Bs[2][TM * BK];
    const int tid  = threadIdx.x;
    const int lane = tid & 63;
    const int wv   = tid >> 6;
    const int l16  = lane & 15;
    const int quad = lane >> 4;
    const int wm   = (wv >> 1) * 64;
    const int wn   = (wv & 1) * 64;

    f32x4 acc[4][4];
#pragma unroll
    for (int i = 0; i < 4; i++)
#pragma unroll
        for (int j = 0; j < 4; j++) acc[i][j] = {};

    // staging: one gld covers 8 rows x 64 cols (64 lanes x 16B). 8 lanes/row.
    const int sr  = lane >> 3;                 // row within 8-row group
    const int sc7 = (lane & 7) ^ sr;           // swizzled source col8
    // wave wv stages rows [wv*32, wv*32+32) of A and B (4 glds each)
    const u16* gA = A + (size_t)(m0 + wv * 32 + sr) * DMODEL + sc7 * 8;
    const u16* gB = W + (size_t)(n0 + wv * 32 + sr) * DMODEL + sc7 * 8;
    const int lofs = wv * 32 * BK;             // wave-uniform LDS offset

    // fragment-read swizzled col8
    const int cA = quad ^ (l16 & 7);          // k in [0,32)
    const int cB = (quad + 4) ^ (l16 & 7);    // k in [32,64)

    // prologue: stage K-tile 0 into buf 0, drain, barrier
#pragma unroll
    for (int g = 0; g < 4; g++) {
        gld_lds16(gA + (size_t)(g * 8) * DMODEL, &As[0][lofs + g * 8 * BK]);
        gld_lds16(gB + (size_t)(g * 8) * DMODEL, &Bs[0][lofs + g * 8 * BK]);
    }
    __builtin_amdgcn_s_waitcnt(0x0F70);   // vmcnt(0)
    __syncthreads();

    int buf = 0;
    for (int kb = 0; kb < DMODEL; kb += BK) {
        const bool more = (kb + BK < DMODEL);
        if (more) {   // stage NEXT tile into the other buffer, issue-early
#pragma unroll
            for (int g = 0; g < 4; g++) {
                gld_lds16(gA + kb + BK + (size_t)(g * 8) * DMODEL,
                          &As[buf ^ 1][lofs + g * 8 * BK]);
                gld_lds16(gB + kb + BK + (size_t)(g * 8) * DMODEL,
                          &Bs[buf ^ 1][lofs + g * 8 * BK]);
            }
        }
        __builtin_amdgcn_sched_barrier(0);   // pin stage-issue before compute

        bf16x8 af0[4], af1[4], bf0[4], bf1[4];
#pragma unroll
        for (int i = 0; i < 4; i++) {
            const u16* ap = &As[buf][(wm + i * 16 + l16) * BK];
            af0[i] = *(const bf16x8*)(ap + cA * 8);
            af1[i] = *(const bf16x8*)(ap + cB * 8);
        }
#pragma unroll
        for (int j = 0; j < 4; j++) {
            const u16* bp = &Bs[buf][(wn + j * 16 + l16) * BK];
            bf0[j] = *(const bf16x8*)(bp + cA * 8);
            bf1[j] = *(const bf16x8*)(bp + cB * 8);
        }
#pragma unroll
        for (int i = 0; i < 4; i++)
#pragma unroll
            for (int j = 0; j < 4; j++)
                acc[i][j] = __builtin_amdgcn_mfma_f32_16x16x32_bf16(af0[i], bf0[j], acc[i][j], 0, 0, 0);
#pragma unroll
        for (int i = 0; i < 4; i++)
#pragma unroll
            for (int j = 0; j < 4; j++)
                acc[i][j] = __builtin_amdgcn_mfma_f32_16x16x32_bf16(af1[i], bf1[j], acc[i][j], 0, 0, 0);

        if (more) __builtin_amdgcn_s_waitcnt(0x0F70);   // vmcnt(0): next staged
        __syncthreads();
        buf ^= 1;
    }

#pragma unroll
    for (int j = 0; j < 4; j++) {
        int n = n0 + wn + j * 16 + l16;
        float bv = bias[n];
#pragma unroll
        for (int i = 0; i < 4; i++) {
            int mbase = m0 + wm + i * 16 + quad * 4;
#pragma unroll
            for (int r = 0; r < 4; r++) {
                int m = mbase + r;
                float v = acc[i][j][r] + bv;
                if (mode == 2) {
                    ((float*)outp)[(size_t)m * DMODEL + n] = v;
                } else {
                    int b = m >> 11, s = m & (S_LEN - 1);
                    int h = n >> 6, d = n & 63;
                    u16* o = (u16*)outp;
                    size_t idx = (mode == 0)
                        ? ((((size_t)(b * NHEAD + h)) * S_LEN + s) * HDIM + d)
                        : ((((size_t)(b * NHEAD + h)) * HDIM + d) * S_LEN + s);
                    o[idx] = f2bf(v);
                }
            }
        }
    }
}

// XCD-locality swizzle: XCD (lid&7) owns m-blocks [8*xcd, 8*xcd+8) for ALL n.
__device__ __forceinline__ void gemm_coords(int& m0, int& n0) {
    const int lid = blockIdx.x + 8 * blockIdx.y;   // 0..511
    const int xcd = lid & 7;
    const int s   = lid >> 3;                      // 0..63
    n0 = (s & 7) * TN;
    m0 = ((s >> 3) + 8 * xcd) * TM;
}

__global__ __launch_bounds__(256) void gemm_qkv(
        const u16* __restrict__ xq, const u16* __restrict__ xk, const u16* __restrict__ xv,
        const u16* __restrict__ wq, const u16* __restrict__ wk, const u16* __restrict__ wv,
        const float* __restrict__ bq, const float* __restrict__ bk, const float* __restrict__ bv,
        u16* __restrict__ Qb, u16* __restrict__ Kb, u16* __restrict__ Vb) {
    int z = blockIdx.z;
    const u16* A   = (z == 0) ? xq : (z == 1) ? xk : xv;
    const u16* W   = (z == 0) ? wq : (z == 1) ? wk : wv;
    const float* b = (z == 0) ? bq : (z == 1) ? bk : bv;
    u16* out       = (z == 0) ? Qb : (z == 1) ? Kb : Vb;
    int m0, n0;
    gemm_coords(m0, n0);
    gemm_body(A, W, b, out, (z == 2) ? 1 : 0, m0, n0);
}

__global__ __launch_bounds__(256) void gemm_one(
        const u16* __restrict__ A, const u16* __restrict__ W,
        const float* __restrict__ bias, void* __restrict__ out, int mode) {
    int m0, n0;
    gemm_coords(m0, n0);
    gemm_body(A, W, bias, out, mode, m0, n0);
}

// ---------- flash attention (v5: swapped QK^T -> packed b64 P-writes) ----------
// 1 q-tile (16 queries) per wave; 64-key tiles; block-cooperative K/V LDS
// staging double-buffered via global_load_lds; XOR-swizzled layout; fixed-max
// log2-domain softmax; row sums via ones-operand MFMA; {g, 31-g} pairing ->
// exactly 33 iters/block.
// v5 (this round): QK^T computed as mfma(K, Q) — A/B fragment layouts are
// identical for 16x16x32, so the swap is free; C-output col=l16 becomes the
// QUERY, row=quad*4+r the KEY. Each lane then holds 4 CONSECUTIVE keys per t
// (16t+4*quad+{0..3}) of ONE query row -> P-scatter becomes 4 ds_write_b64
// (was 16 ds_write_u16), and float->bf16 uses native casts so the compiler
// emits v_cvt_pk_bf16_f32 pairs (was ~48 VALU ops of manual RNE).
// P LDS row = l16 (query); slot (2t+(quad>>1))^(l16&7), half (quad&1) keeps
// the standard XOR-swizzle invariant "logical col8 c holds keys 8c..8c+7",
// so the pf0/pf1 fragment reads (and PV/osum/epilogue) are byte-identical.
__global__ __launch_bounds__(256, 4) void flash_kernel(
        const u16* __restrict__ Q, const u16* __restrict__ K,
        const u16* __restrict__ Vt, u16* __restrict__ AO) {
    __shared__ __align__(16) u16 Ksm[2][64 * 64];
    __shared__ __align__(16) u16 Vsm[2][64 * 64];
    __shared__ __align__(16) u16 Psm[4][16 * 64];

    const int tid  = threadIdx.x;
    const int wv   = tid >> 6;
    const int lane = tid & 63;
    const int l16  = lane & 15;
    const int quad = lane >> 4;

    // XCD-pinning: all 16 blocks of a bh share (linear id % 8)
    const int lid   = blockIdx.x + 16 * blockIdx.y;   // 0..1023
    const int xcd   = lid & 7;
    const int slot  = lid >> 3;                        // 0..127
    const int bh    = xcd + 8 * (slot >> 4);           // 0..63
    const int g_idx = slot & 15;                       // 0..15

    const int h    = bh & (NHEAD - 1);
    const int b    = bh >> 4;
    const bool fwd = (h < 8);
    const int sgn  = fwd ? 1 : -1;
    const float slope2 = __builtin_amdgcn_exp2f(-(float)((h & 7) + 1) * 0.5731203125901445f)
                         * 1.4426950408889634f;
    const float cL = 0.18033688011112042f;   // log2(e)/8

    const u16* Kg = K + (size_t)bh * S_LEN * HDIM;
    const u16* Vg = Vt + (size_t)bh * HDIM * S_LEN;

    // staging lane constants: 8 lanes per row, col16 = (lane&7) ^ (lane>>3)
    const int sr = lane >> 3;
    const int sc = (lane & 7) ^ sr;
    const int r0 = 16 * wv;          // this wave stages rows r0..r0+15

    // fragment-read swizzled col16
    const int cA = quad ^ (l16 & 7);          // global col16 = quad
    const int cB = (quad + 4) ^ (l16 & 7);    // global col16 = quad+4

    // ALiBi per-(t,r) in-tile offset (swapped layout: key=16t+4q+r, query=l16)
    float brt[4][4];
#pragma unroll
    for (int t = 0; t < 4; t++)
#pragma unroll
        for (int r = 0; r < 4; r++)
            brt[t][r] = slope2 * (float)(sgn * (16 * t + 4 * quad + r - l16)) - 16.0f;

    // P packed-write offsets (u16 units): row l16, one b64 per t
    int poff4[4];
#pragma unroll
    for (int t = 0; t < 4; t++)
        poff4[t] = l16 * 64 + (((2 * t + (quad >> 1)) ^ (l16 & 7)) * 8) + 4 * (quad & 1);

    bf16x8 ones;
#pragma unroll
    for (int j = 0; j < 8; j++) ones[j] = (__bf16)1.0f;

    const float dkq = slope2 * (float)(sgn * 64);

#pragma unroll 1
    for (int half = 0; half < 2; half++) {
        const int g  = half ? (31 - g_idx) : g_idx;    // 64-query group 0..31
        const int q0 = g * 64 + wv * 16;
        const u16* Qp = Q + ((size_t)bh * S_LEN + q0) * HDIM;
        const bf16x8 aq0 = *(const bf16x8*)(Qp + l16 * HDIM + quad * 8);
        const bf16x8 aq1 = *(const bf16x8*)(Qp + l16 * HDIM + 32 + quad * 8);

        f32x4 o[4], osum = {};
#pragma unroll
        for (int dt = 0; dt < 4; dt++) o[dt] = {};

        const int kt0 = fwd ? 0 : g;
        const int kt1 = fwd ? g : (S_LEN / 64 - 1);

        __syncthreads();   // previous half's readers done before overwrite
        // incremental staging pointers
        const u16* kg = Kg + ((size_t)(kt0 * 64) + r0 + sr) * 64 + sc * 8;
        const u16* vg = Vg + (size_t)(r0 + sr) * S_LEN + kt0 * 64 + sc * 8;
        gld_lds16(kg,              &Ksm[0][r0 * 64]);
        gld_lds16(kg + 8 * 64,     &Ksm[0][(r0 + 8) * 64]);
        gld_lds16(vg,              &Vsm[0][r0 * 64]);
        gld_lds16(vg + 8 * S_LEN,  &Vsm[0][(r0 + 8) * 64]);
        kg += 64 * 64;
        vg += 64;

        float kq = slope2 * (float)(sgn * (kt0 * 64 - q0));

        int buf = 0;
        for (int kt = kt0; kt <= kt1; ++kt) {
            __builtin_amdgcn_s_waitcnt(0x0F70);   // vmcnt(0): buf staged
            __syncthreads();
            if (kt < kt1) {   // stage next tile into the other buffer
                gld_lds16(kg,             &Ksm[buf ^ 1][r0 * 64]);
                gld_lds16(kg + 8 * 64,    &Ksm[buf ^ 1][(r0 + 8) * 64]);
                gld_lds16(vg,             &Vsm[buf ^ 1][r0 * 64]);
                gld_lds16(vg + 8 * S_LEN, &Vsm[buf ^ 1][(r0 + 8) * 64]);
                kg += 64 * 64;
                vg += 64;
            }
            const u16* Ks = &Ksm[buf][0];
            const u16* Vs = &Vsm[buf][0];

            // QK^T from LDS — swapped operands: A=K rows, B=Q rows
            f32x4 st[4];
#pragma unroll
            for (int t = 0; t < 4; t++) {
                const u16* kp = Ks + (16 * t + l16) * 64;
                bf16x8 k0 = *(const bf16x8*)(kp + cA * 8);
                bf16x8 k1 = *(const bf16x8*)(kp + cB * 8);
                f32x4 c = {};
                c = __builtin_amdgcn_mfma_f32_16x16x32_bf16(k0, aq0, c, 0, 0, 0);
                c = __builtin_amdgcn_mfma_f32_16x16x32_bf16(k1, aq1, c, 0, 0, 0);
                st[t] = c;
            }

            float p[4][4];
            if (kt == g) {   // diagonal tile: explicit mask
                const int qg = q0 + l16;
#pragma unroll
                for (int t = 0; t < 4; t++)
#pragma unroll
                    for (int r = 0; r < 4; r++) {
                        const int kg2 = kt * 64 + 16 * t + 4 * quad + r;
                        const bool ok = fwd ? (kg2 <= qg) : (kg2 >= qg);
                        float s2 = fmaf(st[t][r], cL, brt[t][r] + kq);
                        p[t][r] = ok ? __builtin_amdgcn_exp2f(s2) : 0.0f;
                    }
            } else {
#pragma unroll
                for (int t = 0; t < 4; t++)
#pragma unroll
                    for (int r = 0; r < 4; r++)
                        p[t][r] = __builtin_amdgcn_exp2f(fmaf(st[t][r], cL, brt[t][r] + kq));
            }
            kq += dkq;

            // P row (4 consecutive keys per t) -> one b64 write per t
            u16* Pw = &Psm[wv][0];
#pragma unroll
            for (int t = 0; t < 4; t++) {
                bf16x4 pk;
                pk[0] = (__bf16)p[t][0];
                pk[1] = (__bf16)p[t][1];
                pk[2] = (__bf16)p[t][2];
                pk[3] = (__bf16)p[t][3];
                *(bf16x4*)(Pw + poff4[t]) = pk;
            }
            __builtin_amdgcn_s_waitcnt(0xC07F);   // lgkmcnt(0); wave-private
            bf16x8 pf0 = *(const bf16x8*)(&Pw[l16 * 64 + cA * 8]);
            bf16x8 pf1 = *(const bf16x8*)(&Pw[l16 * 64 + cB * 8]);

            // PV from LDS V
#pragma unroll
            for (int dt = 0; dt < 4; dt++) {
                const u16* vp = Vs + (dt * 16 + l16) * 64;
                bf16x8 v0 = *(const bf16x8*)(vp + cA * 8);
                bf16x8 v1 = *(const bf16x8*)(vp + cB * 8);
                o[dt] = __builtin_amdgcn_mfma_f32_16x16x32_bf16(pf0, v0, o[dt], 0, 0, 0);
                o[dt] = __builtin_amdgcn_mfma_f32_16x16x32_bf16(pf1, v1, o[dt], 0, 0, 0);
            }
            osum = __builtin_amdgcn_mfma_f32_16x16x32_bf16(pf0, ones, osum, 0, 0, 0);
            osum = __builtin_amdgcn_mfma_f32_16x16x32_bf16(pf1, ones, osum, 0, 0, 0);
            buf ^= 1;
        }

        // epilogue: AO[b, s, h*64+d] bf16
#pragma unroll
        for (int r = 0; r < 4; r++) {
            float inv = 1.0f / osum[r];
            int qg = q0 + quad * 4 + r;
            u16* op = AO + ((size_t)b * S_LEN + qg) * DMODEL + h * HDIM;
#pragma unroll
            for (int dt = 0; dt < 4; dt++)
                op[dt * 16 + l16] = f2bf(o[dt][r] * inv);
        }
    }
}

extern "C" void kernel_launch(void* const* d_in, const int* in_sizes, int n_in,
                              void* d_out, int out_size, void* d_ws, size_t ws_size,
                              hipStream_t stream) {
    const float* query = (const float*)d_in[0];
    const float* key   = (const float*)d_in[1];
    const float* value = (const float*)d_in[2];
    const float* Wq    = (const float*)d_in[3];
    const float* bq    = (const float*)d_in[4];
    const float* Wk    = (const float*)d_in[5];
    const float* bk    = (const float*)d_in[6];
    const float* Wv    = (const float*)d_in[7];
    const float* bv    = (const float*)d_in[8];
    const float* Wo    = (const float*)d_in[9];
    const float* bo    = (const float*)d_in[10];

    const size_t Xe = (size_t)MTOK * DMODEL;    // 2^23 elems
    const size_t We = (size_t)DMODEL * DMODEL;  // 2^20 elems
    u16* xq  = (u16*)d_ws;
    u16* xk  = xq + Xe;
    u16* xv  = xk + Xe;
    u16* wqb = xv + Xe;
    u16* wkb = wqb + We;
    u16* wvb = wkb + We;
    u16* wob = wvb + We;
    u16* Qb  = wob + We;
    u16* Kb  = Qb + Xe;
    u16* Vb  = Kb + Xe;   // transposed [B,H,D,S]
    u16* AO  = Vb + Xe;

    cast_all<<<dim3(28672), dim3(256), 0, stream>>>(
        query, key, value, Wq, Wk, Wv, Wo,
        xq, xk, xv, wqb, wkb, wvb, wob);

    gemm_qkv<<<dim3(DMODEL / TN, MTOK / TM, 3), dim3(256), 0, stream>>>(
        xq, xk, xv, wqb, wkb, wvb, bq, bk, bv, Qb, Kb, Vb);

    flash_kernel<<<dim3(16, NBATCH * NHEAD), dim3(256), 0, stream>>>(Qb, Kb, Vb, AO);

    gemm_one<<<dim3(DMODEL / TN, MTOK / TM, 1), dim3(256), 0, stream>>>(AO, wob, bo, d_out, 2);
}